// Round 6
// baseline (144.557 us; speedup 1.0000x reference)
//
#include <hip/hip_runtime.h>

typedef __attribute__((ext_vector_type(8))) short bf16x8;
typedef __attribute__((ext_vector_type(4))) float floatx4;

__device__ __forceinline__ unsigned short f2bf(float f) {
    unsigned int u = __float_as_uint(f);
    u += 0x7FFFu + ((u >> 16) & 1u);
    return (unsigned short)(u >> 16);
}

__device__ __forceinline__ int interp_word(int a00, int a01, int a10, int a11,
                                           float w00, float w01, float w10, float w11) {
    float vl = w00 * __uint_as_float((unsigned)a00 << 16)
             + w01 * __uint_as_float((unsigned)a01 << 16)
             + w10 * __uint_as_float((unsigned)a10 << 16)
             + w11 * __uint_as_float((unsigned)a11 << 16);
    float vh = w00 * __uint_as_float((unsigned)a00 & 0xffff0000u)
             + w01 * __uint_as_float((unsigned)a01 & 0xffff0000u)
             + w10 * __uint_as_float((unsigned)a10 & 0xffff0000u)
             + w11 * __uint_as_float((unsigned)a11 & 0xffff0000u);
    return (int)__builtin_amdgcn_perm(__float_as_uint(vh) + 0x8000u,
                                      __float_as_uint(vl) + 0x8000u, 0x07060302u);
}

// async 16B-per-lane global->LDS (no VGPR round trip). LDS base wave-uniform.
__device__ __forceinline__ void g2l16(const unsigned short* g, unsigned short* l) {
    __builtin_amdgcn_global_load_lds(
        (const __attribute__((address_space(1))) unsigned int*)g,
        (__attribute__((address_space(3))) unsigned int*)l, 16, 0, 0);
}

// ---- prep: [0,1024) x->NHWC bf16 | [1024,1312) Wk frag-major | [1312,1384) Woff frag-major ----
__global__ __launch_bounds__(256) void prep_all(const float* __restrict__ x,
        const float* __restrict__ Wk, const float* __restrict__ Woff,
        unsigned short* __restrict__ xt, unsigned short* __restrict__ Wkb2,
        unsigned short* __restrict__ Woffb) {
    int bb = blockIdx.x;
    if (bb < 1024) {
        __shared__ float tile[64][65];
        int b = bb >> 6, y = bb & 63;
        const float* src = x + (size_t)b * 262144 + y * 64;
        int tx = threadIdx.x & 15, tg = threadIdx.x >> 4;
#pragma unroll
        for (int i = 0; i < 4; i++) {
            int c = tg + i * 16;
            float4 v = *(const float4*)(src + (size_t)c * 4096 + tx * 4);
            tile[c][tx * 4 + 0] = v.x; tile[c][tx * 4 + 1] = v.y;
            tile[c][tx * 4 + 2] = v.z; tile[c][tx * 4 + 3] = v.w;
        }
        __syncthreads();
        unsigned short* dst = xt + (size_t)bb * 4096;
#pragma unroll
        for (int i = 0; i < 4; i++) {
            int xc = tg + i * 16;
            int c4 = tx * 4;
            ushort4 v;
            v.x = f2bf(tile[c4 + 0][xc]); v.y = f2bf(tile[c4 + 1][xc]);
            v.z = f2bf(tile[c4 + 2][xc]); v.w = f2bf(tile[c4 + 3][xc]);
            *(ushort4*)(dst + xc * 64 + c4) = v;
        }
    } else if (bb < 1312) {
        int idx = (bb - 1024) * 256 + threadIdx.x;
        int tap = idx >> 13;
        int r = idx & 8191;
        int tile = r >> 9;
        int ln = (r >> 3) & 63;
        int j = r & 7;
        int mt = tile >> 1, kc = tile & 1;
        int oc = mt * 16 + (ln & 15);
        int c = kc * 32 + (ln >> 4) * 8 + j;
        Wkb2[idx] = f2bf(Wk[(oc * 64 + c) * 9 + tap]);
    } else {
        int idx = (bb - 1312) * 256 + threadIdx.x;
        int tap = idx >> 11;
        int r = idx & 2047;
        int tile = r >> 9;
        int ln = (r >> 3) & 63;
        int j = r & 7;
        int mt = tile >> 1, kc = tile & 1;
        int n = mt * 16 + (ln & 15);
        int c = kc * 32 + (ln >> 4) * 8 + j;
        float v = (n < 18) ? Woff[(n * 64 + c) * 9 + tap] : 0.f;
        Woffb[idx] = f2bf(v);
    }
}

// ==================== PHASE A: sampler ====================
// Per block: 64 px of one image. GEMM1 offsets (R5-proven, wave-private offs,
// no barrier), then per tap: 8 scattered gathers -> interp -> coalesced store of
// the sampled B-matrix xo[tap][chunk_px][64ch] (bf16, exact MFMA input values).
// No MFMA-wait coupling, low VGPR -> 4 waves/EU TLP hides gather latency.
__global__ __launch_bounds__(256, 4) void sampler_kernel(
        const unsigned short* __restrict__ xt,
        const unsigned short* __restrict__ Woffb,
        const float* __restrict__ boff,
        unsigned short* __restrict__ xo,
        int b0, int chunkpx) {
    __shared__ float offs[64][20];
    int tid = threadIdx.x;
    int wave = tid >> 6, lane = tid & 63;
    int frow = lane & 15, quad = lane >> 4;
    int nwg = gridDim.x;
    int bb = (blockIdx.x & 7) * (nwg >> 3) + (blockIdx.x >> 3);  // XCD swizzle
    int bLoc = bb >> 6;
    int b = b0 + bLoc;
    int pxBase = (bb & 63) * 64;
    int pl = wave * 16 + frow;
    int px = pxBase + pl;
    int y = px >> 6, xx = px & 63;
    const char* img = (const char*)(xt + (size_t)b * 262144) + quad * 16;

    float bv[2][4];
#pragma unroll
    for (int mt = 0; mt < 2; mt++)
#pragma unroll
        for (int rg = 0; rg < 4; rg++) {
            int n = mt * 16 + quad * 4 + rg;
            bv[mt][rg] = (n < 18) ? boff[n] : 0.f;
        }

    // GEMM1: offset conv, direct-global A, no barriers
    floatx4 acc1[2];
    acc1[0] = (floatx4)(0.f); acc1[1] = (floatx4)(0.f);
#pragma unroll
    for (int tap = 0; tap < 9; tap++) {
        int ry = y + tap / 3 - 1, rx = xx + tap % 3 - 1;
        bool valid = (ry >= 0) & (ry < 64) & (rx >= 0) & (rx < 64);
        const char* src = img + ((ry * 64 + rx) << 7);
        const unsigned short* wofft = Woffb + tap * 2048 + lane * 8;
        bf16x8 bz = {};
#pragma unroll
        for (int kc = 0; kc < 2; kc++) {
            bf16x8 bfr = valid ? *(const bf16x8*)(src + kc * 64) : bz;
#pragma unroll
            for (int mt = 0; mt < 2; mt++) {
                bf16x8 af = *(const bf16x8*)(wofft + (mt * 2 + kc) * 512);
                acc1[mt] = __builtin_amdgcn_mfma_f32_16x16x32_bf16(af, bfr, acc1[mt], 0, 0, 0);
            }
        }
    }
    // offs wave-private (writer wave == reader wave) -> no barrier
#pragma unroll
    for (int mt = 0; mt < 2; mt++)
#pragma unroll
        for (int rg = 0; rg < 4; rg++) {
            int n = mt * 16 + quad * 4 + rg;
            if (n < 18) offs[pl][n] = acc1[mt][rg] + bv[mt][rg];
        }

    const float* op = &offs[pl][0];

    // taps: gather -> interp -> store. Serial per wave; TLP (16 waves/CU) hides latency.
#pragma unroll 1
    for (int tap = 0; tap < 9; tap++) {
        float orow = op[tap];
        float ocol = op[9 + tap];
        float pr = (float)(y + tap / 3 - 1) + orow;
        float pc = (float)(xx + tap % 3 - 1) + ocol;
        pr = fminf(fmaxf(pr, 0.f), 63.f);
        pc = fminf(fmaxf(pc, 0.f), 63.f);
        float fr = floorf(pr), fc = floorf(pc);
        float tr = pr - fr, tc = pc - fc;
        int r0 = (int)fr, c0 = (int)fc;
        int r1 = min(r0 + 1, 63), c1 = min(c0 + 1, 63);
        float w00 = (1.f - tr) * (1.f - tc);
        float w01 = (1.f - tr) * tc;
        float w10 = tr * (1.f - tc);
        float w11 = tr * tc;
        const char* p00 = img + ((r0 * 64 + c0) << 7);
        const char* p01 = img + ((r0 * 64 + c1) << 7);
        const char* p10 = img + ((r1 * 64 + c0) << 7);
        const char* p11 = img + ((r1 * 64 + c1) << 7);
        int4 g00[2], g01[2], g10[2], g11[2];
#pragma unroll
        for (int kc = 0; kc < 2; kc++) {
            g00[kc] = *(const int4*)(p00 + kc * 64);
            g01[kc] = *(const int4*)(p01 + kc * 64);
            g10[kc] = *(const int4*)(p10 + kc * 64);
            g11[kc] = *(const int4*)(p11 + kc * 64);
        }
        unsigned short* dst = xo + (size_t)(tap * chunkpx + bLoc * 4096 + px) * 64 + quad * 8;
#pragma unroll
        for (int kc = 0; kc < 2; kc++) {
            int4 r;
            r.x = interp_word(g00[kc].x, g01[kc].x, g10[kc].x, g11[kc].x, w00, w01, w10, w11);
            r.y = interp_word(g00[kc].y, g01[kc].y, g10[kc].y, g11[kc].y, w00, w01, w10, w11);
            r.z = interp_word(g00[kc].z, g01[kc].z, g10[kc].z, g11[kc].z, w00, w01, w10, w11);
            r.w = interp_word(g00[kc].w, g01[kc].w, g10[kc].w, g11[kc].w, w00, w01, w10, w11);
            *(bf16x8*)(dst + kc * 32) = __builtin_bit_cast(bf16x8, r);
        }
    }
}

// ==================== PHASE B: dense GEMM ====================
// C[128 oc][chunkpx] = sum_{tap,ch} A[tap][oc][ch] * xo[tap][px][ch] + bias.
// Block: 256 thr / 4 waves, tile M=128 x N=128 (wave: M=128 x N=32, 2 n-tiles).
// A staged per tap via global_load_lds double-buffer + counted vmcnt (R5 template);
// B: clean coalesced 1KB loads, 2-deep pipelined. 32 MFMA per wave-tap.
__global__ __launch_bounds__(256, 3) void gemm_kernel(
        const unsigned short* __restrict__ xo,
        const unsigned short* __restrict__ Wkb2,
        const float* __restrict__ bias,
        float* __restrict__ out,
        int b0, int chunkpx) {
    __shared__ unsigned short As0[8192];
    __shared__ unsigned short As1[8192];
    int tid = threadIdx.x;
    int wave = tid >> 6, lane = tid & 63;
    int frow = lane & 15, quad = lane >> 4;
    int nwg = gridDim.x;
    int bb = (blockIdx.x & 7) * (nwg >> 3) + (blockIdx.x >> 3);  // XCD swizzle
    int P = bb * 128 + wave * 32;                  // chunk-px base of this wave

    floatx4 acc[8][2];
#pragma unroll
    for (int mt = 0; mt < 8; mt++) { acc[mt][0] = (floatx4)(0.f); acc[mt][1] = (floatx4)(0.f); }

    const unsigned short* bbase = xo + (size_t)(P + frow) * 64 + quad * 8;

    bf16x8 bcur[2][2], bnxt[2][2];                 // [nt][kc]
#define LOAD_B(DST, TAP) do {                                                   \
        const unsigned short* p_ = bbase + (size_t)(TAP) * chunkpx * 64;        \
        DST[0][0] = *(const bf16x8*)(p_);                                       \
        DST[0][1] = *(const bf16x8*)(p_ + 32);                                  \
        DST[1][0] = *(const bf16x8*)(p_ + 1024);                                \
        DST[1][1] = *(const bf16x8*)(p_ + 1056);                                \
    } while (0)

#define STAGE_A(BUF, TAP) do {                                                  \
        const unsigned short* gs_ = Wkb2 + (TAP) * 8192 + wave * 2048 + lane * 8; \
        g2l16(gs_,        &BUF[wave * 2048]);                                   \
        g2l16(gs_ + 512,  &BUF[wave * 2048 + 512]);                             \
        g2l16(gs_ + 1024, &BUF[wave * 2048 + 1024]);                            \
        g2l16(gs_ + 1536, &BUF[wave * 2048 + 1536]);                            \
    } while (0)

    // Per-tap body. Steady outstanding at wait: S(t)=4 + B(t)=4 -> vmcnt(4)
    // drains staging only; B(t) drained by compiler before first MFMA use;
    // S(t+1)/B(t+1) stay in flight across the whole MFMA block.
#define BODY(TAP, RBUF, WBUF, LAST) do {                                        \
        asm volatile("s_waitcnt vmcnt(4)\n\ts_barrier" ::: "memory");           \
        if (!(LAST)) { STAGE_A(WBUF, (TAP) + 1); LOAD_B(bnxt, (TAP) + 1); }     \
        __builtin_amdgcn_sched_barrier(0);                                      \
        _Pragma("unroll")                                                       \
        for (int kc = 0; kc < 2; kc++)                                          \
            _Pragma("unroll")                                                   \
            for (int mt = 0; mt < 8; mt++) {                                    \
                bf16x8 af = *(const bf16x8*)&RBUF[(mt * 2 + kc) * 512 + lane * 8]; \
                acc[mt][0] = __builtin_amdgcn_mfma_f32_16x16x32_bf16(af, bcur[0][kc], acc[mt][0], 0, 0, 0); \
                acc[mt][1] = __builtin_amdgcn_mfma_f32_16x16x32_bf16(af, bcur[1][kc], acc[mt][1], 0, 0, 0); \
            }                                                                   \
        if (!(LAST)) {                                                          \
            _Pragma("unroll")                                                   \
            for (int nt = 0; nt < 2; nt++) {                                    \
                bcur[nt][0] = bnxt[nt][0]; bcur[nt][1] = bnxt[nt][1];           \
            }                                                                   \
        }                                                                       \
    } while (0)

    STAGE_A(As0, 0);
    LOAD_B(bcur, 0);

#pragma unroll 1
    for (int t2 = 0; t2 < 4; t2++) {
        int tap = t2 * 2;
        BODY(tap,     As0, As1, false);
        BODY(tap + 1, As1, As0, false);
    }
    BODY(8, As0, As1, true);

#undef BODY
#undef STAGE_A
#undef LOAD_B

    // epilogue: b from chunk px; px within image; D col=frow, row=quad*4+rg
    int b = b0 + (P >> 12);
    int pxi = P & 4095;
    float* outb = out + (size_t)b * 524288 + pxi + frow;
#pragma unroll
    for (int mt = 0; mt < 8; mt++) {
        float4 bc = *(const float4*)(bias + mt * 16 + quad * 4);
        float bcv[4] = {bc.x, bc.y, bc.z, bc.w};
#pragma unroll
        for (int nt = 0; nt < 2; nt++)
#pragma unroll
            for (int rg = 0; rg < 4; rg++) {
                int oc = mt * 16 + quad * 4 + rg;
                outb[oc * 4096 + nt * 16] = acc[mt][nt][rg] + bcv[rg];
            }
    }
}

// ==================== fallback: R5 fused kernel (used only if ws too small) ====
__global__ __launch_bounds__(256, 3) void fused_fallback(
        const unsigned short* __restrict__ xt,
        const unsigned short* __restrict__ Wkb2,
        const unsigned short* __restrict__ Woffb,
        const float* __restrict__ boff,
        const float* __restrict__ bias,
        float* __restrict__ out) {
    __shared__ unsigned short As0[8192];
    __shared__ unsigned short As1[8192];
    __shared__ float offs[64][20];
    int tid = threadIdx.x;
    int wave = tid >> 6, lane = tid & 63;
    int frow = lane & 15, quad = lane >> 4;
    int bb = blockIdx.x;
    int xcd = bb & 7, idx = bb >> 3;
    int b = xcd * 2 + (idx >> 6);
    int pxBase = (idx & 63) * 64;
    int pl = wave * 16 + frow;
    int px = pxBase + pl;
    int y = px >> 6, xx = px & 63;
    const char* img = (const char*)(xt + (size_t)b * 262144) + quad * 16;

    float bv[2][4];
#pragma unroll
    for (int mt = 0; mt < 2; mt++)
#pragma unroll
        for (int rg = 0; rg < 4; rg++) {
            int n = mt * 16 + quad * 4 + rg;
            bv[mt][rg] = (n < 18) ? boff[n] : 0.f;
        }
    floatx4 acc1[2];
    acc1[0] = (floatx4)(0.f); acc1[1] = (floatx4)(0.f);
#pragma unroll
    for (int tap = 0; tap < 9; tap++) {
        int ry = y + tap / 3 - 1, rx = xx + tap % 3 - 1;
        bool valid = (ry >= 0) & (ry < 64) & (rx >= 0) & (rx < 64);
        const char* src = img + ((ry * 64 + rx) << 7);
        const unsigned short* wofft = Woffb + tap * 2048 + lane * 8;
        bf16x8 bz = {};
#pragma unroll
        for (int kc = 0; kc < 2; kc++) {
            bf16x8 bfr = valid ? *(const bf16x8*)(src + kc * 64) : bz;
#pragma unroll
            for (int mt = 0; mt < 2; mt++) {
                bf16x8 af = *(const bf16x8*)(wofft + (mt * 2 + kc) * 512);
                acc1[mt] = __builtin_amdgcn_mfma_f32_16x16x32_bf16(af, bfr, acc1[mt], 0, 0, 0);
            }
        }
    }
#pragma unroll
    for (int mt = 0; mt < 2; mt++)
#pragma unroll
        for (int rg = 0; rg < 4; rg++) {
            int n = mt * 16 + quad * 4 + rg;
            if (n < 18) offs[pl][n] = acc1[mt][rg] + bv[mt][rg];
        }
    floatx4 acc[8];
#pragma unroll
    for (int i = 0; i < 8; i++) acc[i] = (floatx4)(0.f);
    const float* op = &offs[pl][0];
    auto stage = [&](int tap, int4 (&r00)[2], int4 (&r01)[2], int4 (&r10)[2],
                     int4 (&r11)[2], floatx4& w) {
        float orow = op[tap];
        float ocol = op[9 + tap];
        float pr = (float)(y + tap / 3 - 1) + orow;
        float pc = (float)(xx + tap % 3 - 1) + ocol;
        pr = fminf(fmaxf(pr, 0.f), 63.f);
        pc = fminf(fmaxf(pc, 0.f), 63.f);
        float fr = floorf(pr), fc = floorf(pc);
        float tr = pr - fr, tc = pc - fc;
        int r0 = (int)fr, c0 = (int)fc;
        int r1 = min(r0 + 1, 63), c1 = min(c0 + 1, 63);
        w[0] = (1.f - tr) * (1.f - tc);
        w[1] = (1.f - tr) * tc;
        w[2] = tr * (1.f - tc);
        w[3] = tr * tc;
        const char* p00 = img + ((r0 * 64 + c0) << 7);
        const char* p01 = img + ((r0 * 64 + c1) << 7);
        const char* p10 = img + ((r1 * 64 + c0) << 7);
        const char* p11 = img + ((r1 * 64 + c1) << 7);
#pragma unroll
        for (int kc = 0; kc < 2; kc++) {
            r00[kc] = *(const int4*)(p00 + kc * 64);
            r01[kc] = *(const int4*)(p01 + kc * 64);
            r10[kc] = *(const int4*)(p10 + kc * 64);
            r11[kc] = *(const int4*)(p11 + kc * 64);
        }
    };
    auto makeB = [&](int4 (&a00)[2], int4 (&a01)[2], int4 (&a10)[2], int4 (&a11)[2],
                     floatx4& w, bf16x8& b0, bf16x8& b1) {
#pragma unroll
        for (int kc = 0; kc < 2; kc++) {
            int4 r;
            r.x = interp_word(a00[kc].x, a01[kc].x, a10[kc].x, a11[kc].x, w[0], w[1], w[2], w[3]);
            r.y = interp_word(a00[kc].y, a01[kc].y, a10[kc].y, a11[kc].y, w[0], w[1], w[2], w[3]);
            r.z = interp_word(a00[kc].z, a01[kc].z, a10[kc].z, a11[kc].z, w[0], w[1], w[2], w[3]);
            r.w = interp_word(a00[kc].w, a01[kc].w, a10[kc].w, a11[kc].w, w[0], w[1], w[2], w[3]);
            if (kc == 0) b0 = __builtin_bit_cast(bf16x8, r);
            else         b1 = __builtin_bit_cast(bf16x8, r);
        }
    };
    int4 c00[2], c01[2], c10[2], c11[2];
    int4 n00[2], n01[2], n10[2], n11[2];
    floatx4 cw, nw;
#define STAGE_A(BUF, TAP) do {                                                 \
        const unsigned short* gs_ = Wkb2 + (TAP) * 8192 + wave * 2048 + lane * 8; \
        g2l16(gs_,         &BUF[wave * 2048]);                                 \
        g2l16(gs_ + 512,   &BUF[wave * 2048 + 512]);                           \
        g2l16(gs_ + 1024,  &BUF[wave * 2048 + 1024]);                          \
        g2l16(gs_ + 1536,  &BUF[wave * 2048 + 1536]);                          \
    } while (0)
#define BODY(TAP, RBUF, WBUF, LAST) do {                                       \
        asm volatile("s_waitcnt vmcnt(8)\n\ts_barrier" ::: "memory");          \
        if (!(LAST)) { STAGE_A(WBUF, (TAP) + 1); }                             \
        __builtin_amdgcn_sched_barrier(0);                                     \
        if (!(LAST)) stage((TAP) + 1, n00, n01, n10, n11, nw);                 \
        __builtin_amdgcn_sched_barrier(0);                                     \
        bf16x8 bf0, bf1;                                                       \
        makeB(c00, c01, c10, c11, cw, bf0, bf1);                               \
        _Pragma("unroll")                                                      \
        for (int mt = 0; mt < 8; mt++) {                                       \
            bf16x8 af = *(const bf16x8*)&RBUF[(mt * 2) * 512 + lane * 8];      \
            acc[mt] = __builtin_amdgcn_mfma_f32_16x16x32_bf16(af, bf0, acc[mt], 0, 0, 0); \
        }                                                                      \
        _Pragma("unroll")                                                      \
        for (int mt = 0; mt < 8; mt++) {                                       \
            bf16x8 af = *(const bf16x8*)&RBUF[(mt * 2 + 1) * 512 + lane * 8];  \
            acc[mt] = __builtin_amdgcn_mfma_f32_16x16x32_bf16(af, bf1, acc[mt], 0, 0, 0); \
        }                                                                      \
        if (!(LAST)) {                                                         \
            _Pragma("unroll")                                                  \
            for (int kc = 0; kc < 2; kc++) {                                   \
                c00[kc] = n00[kc]; c01[kc] = n01[kc];                          \
                c10[kc] = n10[kc]; c11[kc] = n11[kc];                          \
            }                                                                  \
            cw = nw;                                                           \
        }                                                                      \
    } while (0)
    __builtin_amdgcn_sched_barrier(0);
    STAGE_A(As0, 0);
    __builtin_amdgcn_sched_barrier(0);
    stage(0, c00, c01, c10, c11, cw);
#pragma unroll 1
    for (int t2 = 0; t2 < 4; t2++) {
        int tap = t2 * 2;
        BODY(tap,     As0, As1, false);
        BODY(tap + 1, As1, As0, false);
    }
    BODY(8, As0, As1, true);
#undef BODY
#undef STAGE_A
    float* outb = out + (size_t)b * 524288 + px;
#pragma unroll
    for (int mt = 0; mt < 8; mt++) {
        float4 bc = *(const float4*)(bias + mt * 16 + quad * 4);
        float bcv[4] = {bc.x, bc.y, bc.z, bc.w};
#pragma unroll
        for (int rg = 0; rg < 4; rg++) {
            int oc = mt * 16 + quad * 4 + rg;
            outb[oc * 4096] = acc[mt][rg] + bcv[rg];
        }
    }
}

extern "C" void kernel_launch(void* const* d_in, const int* in_sizes, int n_in,
                              void* d_out, int out_size, void* d_ws, size_t ws_size,
                              hipStream_t stream) {
    const float* x    = (const float*)d_in[0];
    const float* Woff = (const float*)d_in[1];
    const float* boff = (const float*)d_in[2];
    const float* Wk   = (const float*)d_in[3];
    const float* bk   = (const float*)d_in[4];
    float* out = (float*)d_out;

    char* ws = (char*)d_ws;
    unsigned short* xt    = (unsigned short*)ws;               // 8388608 B
    unsigned short* Wkb2  = (unsigned short*)(ws + 8388608);   // 147456 B
    unsigned short* Woffb = (unsigned short*)(ws + 8536064);   // 36864 B
    const size_t base = 8572928;                               // end of fixed region
    unsigned short* xo    = (unsigned short*)(ws + base);      // sampled B-matrix

    prep_all<<<1384, 256, 0, stream>>>(x, Wk, Woff, xt, Wkb2, Woffb);

    // pick largest image-chunk G whose xo fits the workspace
    const size_t per_img = (size_t)9 * 4096 * 64 * 2;          // 4,718,592 B
    int G = 0;
    for (int g = 16; g >= 1; g >>= 1)
        if (ws_size >= base + (size_t)g * per_img) { G = g; break; }

    if (G == 0) {
        fused_fallback<<<1024, 256, 0, stream>>>(xt, Wkb2, Woffb, boff, bk, out);
        return;
    }
    int chunkpx = G * 4096;
    for (int b0 = 0; b0 < 16; b0 += G) {
        sampler_kernel<<<G * 64, 256, 0, stream>>>(xt, Woffb, boff, xo, b0, chunkpx);
        gemm_kernel<<<G * 32, 256, 0, stream>>>(xo, Wkb2, bk, out, b0, chunkpx);
    }
}

// Round 7
// 144.102 us; speedup vs baseline: 1.0032x; 1.0032x over previous
//
#include <hip/hip_runtime.h>

typedef __attribute__((ext_vector_type(8))) short bf16x8;
typedef __attribute__((ext_vector_type(4))) float floatx4;

__device__ __forceinline__ unsigned short f2bf(float f) {
    unsigned int u = __float_as_uint(f);
    u += 0x7FFFu + ((u >> 16) & 1u);
    return (unsigned short)(u >> 16);
}

__device__ __forceinline__ int interp_word(int a00, int a01, int a10, int a11,
                                           float w00, float w01, float w10, float w11) {
    float vl = w00 * __uint_as_float((unsigned)a00 << 16)
             + w01 * __uint_as_float((unsigned)a01 << 16)
             + w10 * __uint_as_float((unsigned)a10 << 16)
             + w11 * __uint_as_float((unsigned)a11 << 16);
    float vh = w00 * __uint_as_float((unsigned)a00 & 0xffff0000u)
             + w01 * __uint_as_float((unsigned)a01 & 0xffff0000u)
             + w10 * __uint_as_float((unsigned)a10 & 0xffff0000u)
             + w11 * __uint_as_float((unsigned)a11 & 0xffff0000u);
    return (int)__builtin_amdgcn_perm(__float_as_uint(vh) + 0x8000u,
                                      __float_as_uint(vl) + 0x8000u, 0x07060302u);
}

// async 16B-per-lane global->LDS (no VGPR round trip). LDS base wave-uniform.
__device__ __forceinline__ void g2l16(const unsigned short* g, unsigned short* l) {
    __builtin_amdgcn_global_load_lds(
        (const __attribute__((address_space(1))) unsigned int*)g,
        (__attribute__((address_space(3))) unsigned int*)l, 16, 0, 0);
}

// ---- prep: [0,1024) x->NHWC bf16 | [1024,1312) Wk frag-major | [1312,1384) Woff frag-major ----
__global__ __launch_bounds__(256) void prep_all(const float* __restrict__ x,
        const float* __restrict__ Wk, const float* __restrict__ Woff,
        unsigned short* __restrict__ xt, unsigned short* __restrict__ Wkb2,
        unsigned short* __restrict__ Woffb) {
    int bb = blockIdx.x;
    if (bb < 1024) {
        __shared__ float tile[64][65];
        int b = bb >> 6, y = bb & 63;
        const float* src = x + (size_t)b * 262144 + y * 64;
        int tx = threadIdx.x & 15, tg = threadIdx.x >> 4;
#pragma unroll
        for (int i = 0; i < 4; i++) {
            int c = tg + i * 16;
            float4 v = *(const float4*)(src + (size_t)c * 4096 + tx * 4);
            tile[c][tx * 4 + 0] = v.x; tile[c][tx * 4 + 1] = v.y;
            tile[c][tx * 4 + 2] = v.z; tile[c][tx * 4 + 3] = v.w;
        }
        __syncthreads();
        unsigned short* dst = xt + (size_t)bb * 4096;
#pragma unroll
        for (int i = 0; i < 4; i++) {
            int xc = tg + i * 16;
            int c4 = tx * 4;
            ushort4 v;
            v.x = f2bf(tile[c4 + 0][xc]); v.y = f2bf(tile[c4 + 1][xc]);
            v.z = f2bf(tile[c4 + 2][xc]); v.w = f2bf(tile[c4 + 3][xc]);
            *(ushort4*)(dst + xc * 64 + c4) = v;
        }
    } else if (bb < 1312) {
        int idx = (bb - 1024) * 256 + threadIdx.x;
        int tap = idx >> 13;
        int r = idx & 8191;
        int tile = r >> 9;
        int ln = (r >> 3) & 63;
        int j = r & 7;
        int mt = tile >> 1, kc = tile & 1;
        int oc = mt * 16 + (ln & 15);
        int c = kc * 32 + (ln >> 4) * 8 + j;
        Wkb2[idx] = f2bf(Wk[(oc * 64 + c) * 9 + tap]);
    } else {
        int idx = (bb - 1312) * 256 + threadIdx.x;
        int tap = idx >> 11;
        int r = idx & 2047;
        int tile = r >> 9;
        int ln = (r >> 3) & 63;
        int j = r & 7;
        int mt = tile >> 1, kc = tile & 1;
        int n = mt * 16 + (ln & 15);
        int c = kc * 32 + (ln >> 4) * 8 + j;
        float v = (n < 18) ? Woff[(n * 64 + c) * 9 + tap] : 0.f;
        Woffb[idx] = f2bf(v);
    }
}

// ==================== PHASE A: sampler (2-deep pipelined tap loop) ====================
// Per block: 64 px of one image. GEMM1 offsets (wave-private offs, no barrier),
// then per tap: issue tap t+1's 8 scattered gathers (pinned early via
// sched_barrier), interp tap t, coalesced store. Gathers get a full
// interp+store+addr window in flight. No MFMA state -> regs ~135 fit
// launch_bounds(256,3) with no spills (R4's failure mode had af[16]+acc[8] too).
__global__ __launch_bounds__(256, 3) void sampler_kernel(
        const unsigned short* __restrict__ xt,
        const unsigned short* __restrict__ Woffb,
        const float* __restrict__ boff,
        unsigned short* __restrict__ xo,
        int b0, int chunkpx) {
    __shared__ float offs[64][20];
    int tid = threadIdx.x;
    int wave = tid >> 6, lane = tid & 63;
    int frow = lane & 15, quad = lane >> 4;
    int nwg = gridDim.x;
    int bb = (blockIdx.x & 7) * (nwg >> 3) + (blockIdx.x >> 3);  // XCD swizzle
    int bLoc = bb >> 6;
    int b = b0 + bLoc;
    int pxBase = (bb & 63) * 64;
    int pl = wave * 16 + frow;
    int px = pxBase + pl;
    int y = px >> 6, xx = px & 63;
    const char* img = (const char*)(xt + (size_t)b * 262144) + quad * 16;

    float bv[2][4];
#pragma unroll
    for (int mt = 0; mt < 2; mt++)
#pragma unroll
        for (int rg = 0; rg < 4; rg++) {
            int n = mt * 16 + quad * 4 + rg;
            bv[mt][rg] = (n < 18) ? boff[n] : 0.f;
        }

    // GEMM1: offset conv, direct-global A, no barriers
    floatx4 acc1[2];
    acc1[0] = (floatx4)(0.f); acc1[1] = (floatx4)(0.f);
#pragma unroll
    for (int tap = 0; tap < 9; tap++) {
        int ry = y + tap / 3 - 1, rx = xx + tap % 3 - 1;
        bool valid = (ry >= 0) & (ry < 64) & (rx >= 0) & (rx < 64);
        const char* src = img + ((ry * 64 + rx) << 7);
        const unsigned short* wofft = Woffb + tap * 2048 + lane * 8;
        bf16x8 bz = {};
#pragma unroll
        for (int kc = 0; kc < 2; kc++) {
            bf16x8 bfr = valid ? *(const bf16x8*)(src + kc * 64) : bz;
#pragma unroll
            for (int mt = 0; mt < 2; mt++) {
                bf16x8 af = *(const bf16x8*)(wofft + (mt * 2 + kc) * 512);
                acc1[mt] = __builtin_amdgcn_mfma_f32_16x16x32_bf16(af, bfr, acc1[mt], 0, 0, 0);
            }
        }
    }
    // offs wave-private (writer wave == reader wave) -> no barrier
#pragma unroll
    for (int mt = 0; mt < 2; mt++)
#pragma unroll
        for (int rg = 0; rg < 4; rg++) {
            int n = mt * 16 + quad * 4 + rg;
            if (n < 18) offs[pl][n] = acc1[mt][rg] + bv[mt][rg];
        }

    const float* op = &offs[pl][0];

    // stage(tap): bilinear weights + issue the 8 scattered corner loads
    auto stage = [&](int tap, int4 (&r00)[2], int4 (&r01)[2], int4 (&r10)[2],
                     int4 (&r11)[2], floatx4& w) {
        float orow = op[tap];
        float ocol = op[9 + tap];
        float pr = (float)(y + tap / 3 - 1) + orow;
        float pc = (float)(xx + tap % 3 - 1) + ocol;
        pr = fminf(fmaxf(pr, 0.f), 63.f);
        pc = fminf(fmaxf(pc, 0.f), 63.f);
        float fr = floorf(pr), fc = floorf(pc);
        float tr = pr - fr, tc = pc - fc;
        int r0 = (int)fr, c0 = (int)fc;
        int r1 = min(r0 + 1, 63), c1 = min(c0 + 1, 63);
        w[0] = (1.f - tr) * (1.f - tc);
        w[1] = (1.f - tr) * tc;
        w[2] = tr * (1.f - tc);
        w[3] = tr * tc;
        const char* p00 = img + ((r0 * 64 + c0) << 7);
        const char* p01 = img + ((r0 * 64 + c1) << 7);
        const char* p10 = img + ((r1 * 64 + c0) << 7);
        const char* p11 = img + ((r1 * 64 + c1) << 7);
#pragma unroll
        for (int kc = 0; kc < 2; kc++) {
            r00[kc] = *(const int4*)(p00 + kc * 64);
            r01[kc] = *(const int4*)(p01 + kc * 64);
            r10[kc] = *(const int4*)(p10 + kc * 64);
            r11[kc] = *(const int4*)(p11 + kc * 64);
        }
    };

    int4 c00[2], c01[2], c10[2], c11[2];
    floatx4 cw;
    stage(0, c00, c01, c10, c11, cw);

#pragma unroll 1
    for (int tap = 0; tap < 9; tap++) {
        // (1) issue tap t+1's gathers; pin them above interp(t) so they stay
        //     in flight across the interp+store window (R4-proven pin).
        int4 n00[2], n01[2], n10[2], n11[2];
        floatx4 nw;
        if (tap < 8)
            stage(tap + 1, n00, n01, n10, n11, nw);
        __builtin_amdgcn_sched_barrier(0);

        // (2) interp tap t (waits only on gathers issued one iteration ago)
        unsigned short* dst = xo + (size_t)(tap * chunkpx + bLoc * 4096 + px) * 64 + quad * 8;
#pragma unroll
        for (int kc = 0; kc < 2; kc++) {
            int4 r;
            r.x = interp_word(c00[kc].x, c01[kc].x, c10[kc].x, c11[kc].x, cw[0], cw[1], cw[2], cw[3]);
            r.y = interp_word(c00[kc].y, c01[kc].y, c10[kc].y, c11[kc].y, cw[0], cw[1], cw[2], cw[3]);
            r.z = interp_word(c00[kc].z, c01[kc].z, c10[kc].z, c11[kc].z, cw[0], cw[1], cw[2], cw[3]);
            r.w = interp_word(c00[kc].w, c01[kc].w, c10[kc].w, c11[kc].w, cw[0], cw[1], cw[2], cw[3]);
            *(bf16x8*)(dst + kc * 32) = __builtin_bit_cast(bf16x8, r);
        }

        // (3) rotate pipeline registers
        if (tap < 8) {
#pragma unroll
            for (int kc = 0; kc < 2; kc++) {
                c00[kc] = n00[kc]; c01[kc] = n01[kc];
                c10[kc] = n10[kc]; c11[kc] = n11[kc];
            }
            cw = nw;
        }
    }
}

// ==================== PHASE B: dense GEMM ====================
// C[128 oc][chunkpx] = sum_{tap,ch} A[tap][oc][ch] * xo[tap][px][ch] + bias.
// Block: 256 thr / 4 waves, tile M=128 x N=128 (wave: M=128 x N=32, 2 n-tiles).
// A staged per tap via global_load_lds double-buffer + counted vmcnt;
// B: clean coalesced 1KB loads, 2-deep pipelined. 32 MFMA per wave-tap.
__global__ __launch_bounds__(256, 3) void gemm_kernel(
        const unsigned short* __restrict__ xo,
        const unsigned short* __restrict__ Wkb2,
        const float* __restrict__ bias,
        float* __restrict__ out,
        int b0, int chunkpx) {
    __shared__ unsigned short As0[8192];
    __shared__ unsigned short As1[8192];
    int tid = threadIdx.x;
    int wave = tid >> 6, lane = tid & 63;
    int frow = lane & 15, quad = lane >> 4;
    int nwg = gridDim.x;
    int bb = (blockIdx.x & 7) * (nwg >> 3) + (blockIdx.x >> 3);  // XCD swizzle
    int P = bb * 128 + wave * 32;                  // chunk-px base of this wave

    floatx4 acc[8][2];
#pragma unroll
    for (int mt = 0; mt < 8; mt++) { acc[mt][0] = (floatx4)(0.f); acc[mt][1] = (floatx4)(0.f); }

    const unsigned short* bbase = xo + (size_t)(P + frow) * 64 + quad * 8;

    bf16x8 bcur[2][2], bnxt[2][2];                 // [nt][kc]
#define LOAD_B(DST, TAP) do {                                                   \
        const unsigned short* p_ = bbase + (size_t)(TAP) * chunkpx * 64;        \
        DST[0][0] = *(const bf16x8*)(p_);                                       \
        DST[0][1] = *(const bf16x8*)(p_ + 32);                                  \
        DST[1][0] = *(const bf16x8*)(p_ + 1024);                                \
        DST[1][1] = *(const bf16x8*)(p_ + 1056);                                \
    } while (0)

#define STAGE_A(BUF, TAP) do {                                                  \
        const unsigned short* gs_ = Wkb2 + (TAP) * 8192 + wave * 2048 + lane * 8; \
        g2l16(gs_,        &BUF[wave * 2048]);                                   \
        g2l16(gs_ + 512,  &BUF[wave * 2048 + 512]);                             \
        g2l16(gs_ + 1024, &BUF[wave * 2048 + 1024]);                            \
        g2l16(gs_ + 1536, &BUF[wave * 2048 + 1536]);                            \
    } while (0)

#define BODY(TAP, RBUF, WBUF, LAST) do {                                        \
        asm volatile("s_waitcnt vmcnt(4)\n\ts_barrier" ::: "memory");           \
        if (!(LAST)) { STAGE_A(WBUF, (TAP) + 1); LOAD_B(bnxt, (TAP) + 1); }     \
        __builtin_amdgcn_sched_barrier(0);                                      \
        _Pragma("unroll")                                                       \
        for (int kc = 0; kc < 2; kc++)                                          \
            _Pragma("unroll")                                                   \
            for (int mt = 0; mt < 8; mt++) {                                    \
                bf16x8 af = *(const bf16x8*)&RBUF[(mt * 2 + kc) * 512 + lane * 8]; \
                acc[mt][0] = __builtin_amdgcn_mfma_f32_16x16x32_bf16(af, bcur[0][kc], acc[mt][0], 0, 0, 0); \
                acc[mt][1] = __builtin_amdgcn_mfma_f32_16x16x32_bf16(af, bcur[1][kc], acc[mt][1], 0, 0, 0); \
            }                                                                   \
        if (!(LAST)) {                                                          \
            _Pragma("unroll")                                                   \
            for (int nt = 0; nt < 2; nt++) {                                    \
                bcur[nt][0] = bnxt[nt][0]; bcur[nt][1] = bnxt[nt][1];           \
            }                                                                   \
        }                                                                       \
    } while (0)

    STAGE_A(As0, 0);
    LOAD_B(bcur, 0);

#pragma unroll 1
    for (int t2 = 0; t2 < 4; t2++) {
        int tap = t2 * 2;
        BODY(tap,     As0, As1, false);
        BODY(tap + 1, As1, As0, false);
    }
    BODY(8, As0, As1, true);

#undef BODY
#undef STAGE_A
#undef LOAD_B

    int b = b0 + (P >> 12);
    int pxi = P & 4095;
    float* outb = out + (size_t)b * 524288 + pxi + frow;
#pragma unroll
    for (int mt = 0; mt < 8; mt++) {
        float4 bc = *(const float4*)(bias + mt * 16 + quad * 4);
        float bcv[4] = {bc.x, bc.y, bc.z, bc.w};
#pragma unroll
        for (int nt = 0; nt < 2; nt++)
#pragma unroll
            for (int rg = 0; rg < 4; rg++) {
                int oc = mt * 16 + quad * 4 + rg;
                outb[oc * 4096 + nt * 16] = acc[mt][nt][rg] + bcv[rg];
            }
    }
}

// ==================== fallback: R5 fused kernel (used only if ws too small) ====
__global__ __launch_bounds__(256, 3) void fused_fallback(
        const unsigned short* __restrict__ xt,
        const unsigned short* __restrict__ Wkb2,
        const unsigned short* __restrict__ Woffb,
        const float* __restrict__ boff,
        const float* __restrict__ bias,
        float* __restrict__ out) {
    __shared__ unsigned short As0[8192];
    __shared__ unsigned short As1[8192];
    __shared__ float offs[64][20];
    int tid = threadIdx.x;
    int wave = tid >> 6, lane = tid & 63;
    int frow = lane & 15, quad = lane >> 4;
    int bb = blockIdx.x;
    int xcd = bb & 7, idx = bb >> 3;
    int b = xcd * 2 + (idx >> 6);
    int pxBase = (idx & 63) * 64;
    int pl = wave * 16 + frow;
    int px = pxBase + pl;
    int y = px >> 6, xx = px & 63;
    const char* img = (const char*)(xt + (size_t)b * 262144) + quad * 16;

    float bv[2][4];
#pragma unroll
    for (int mt = 0; mt < 2; mt++)
#pragma unroll
        for (int rg = 0; rg < 4; rg++) {
            int n = mt * 16 + quad * 4 + rg;
            bv[mt][rg] = (n < 18) ? boff[n] : 0.f;
        }
    floatx4 acc1[2];
    acc1[0] = (floatx4)(0.f); acc1[1] = (floatx4)(0.f);
#pragma unroll
    for (int tap = 0; tap < 9; tap++) {
        int ry = y + tap / 3 - 1, rx = xx + tap % 3 - 1;
        bool valid = (ry >= 0) & (ry < 64) & (rx >= 0) & (rx < 64);
        const char* src = img + ((ry * 64 + rx) << 7);
        const unsigned short* wofft = Woffb + tap * 2048 + lane * 8;
        bf16x8 bz = {};
#pragma unroll
        for (int kc = 0; kc < 2; kc++) {
            bf16x8 bfr = valid ? *(const bf16x8*)(src + kc * 64) : bz;
#pragma unroll
            for (int mt = 0; mt < 2; mt++) {
                bf16x8 af = *(const bf16x8*)(wofft + (mt * 2 + kc) * 512);
                acc1[mt] = __builtin_amdgcn_mfma_f32_16x16x32_bf16(af, bfr, acc1[mt], 0, 0, 0);
            }
        }
    }
#pragma unroll
    for (int mt = 0; mt < 2; mt++)
#pragma unroll
        for (int rg = 0; rg < 4; rg++) {
            int n = mt * 16 + quad * 4 + rg;
            if (n < 18) offs[pl][n] = acc1[mt][rg] + bv[mt][rg];
        }
    floatx4 acc[8];
#pragma unroll
    for (int i = 0; i < 8; i++) acc[i] = (floatx4)(0.f);
    const float* op = &offs[pl][0];
    auto stage = [&](int tap, int4 (&r00)[2], int4 (&r01)[2], int4 (&r10)[2],
                     int4 (&r11)[2], floatx4& w) {
        float orow = op[tap];
        float ocol = op[9 + tap];
        float pr = (float)(y + tap / 3 - 1) + orow;
        float pc = (float)(xx + tap % 3 - 1) + ocol;
        pr = fminf(fmaxf(pr, 0.f), 63.f);
        pc = fminf(fmaxf(pc, 0.f), 63.f);
        float fr = floorf(pr), fc = floorf(pc);
        float tr = pr - fr, tc = pc - fc;
        int r0 = (int)fr, c0 = (int)fc;
        int r1 = min(r0 + 1, 63), c1 = min(c0 + 1, 63);
        w[0] = (1.f - tr) * (1.f - tc);
        w[1] = (1.f - tr) * tc;
        w[2] = tr * (1.f - tc);
        w[3] = tr * tc;
        const char* p00 = img + ((r0 * 64 + c0) << 7);
        const char* p01 = img + ((r0 * 64 + c1) << 7);
        const char* p10 = img + ((r1 * 64 + c0) << 7);
        const char* p11 = img + ((r1 * 64 + c1) << 7);
#pragma unroll
        for (int kc = 0; kc < 2; kc++) {
            r00[kc] = *(const int4*)(p00 + kc * 64);
            r01[kc] = *(const int4*)(p01 + kc * 64);
            r10[kc] = *(const int4*)(p10 + kc * 64);
            r11[kc] = *(const int4*)(p11 + kc * 64);
        }
    };
    auto makeB = [&](int4 (&a00)[2], int4 (&a01)[2], int4 (&a10)[2], int4 (&a11)[2],
                     floatx4& w, bf16x8& b0, bf16x8& b1) {
#pragma unroll
        for (int kc = 0; kc < 2; kc++) {
            int4 r;
            r.x = interp_word(a00[kc].x, a01[kc].x, a10[kc].x, a11[kc].x, w[0], w[1], w[2], w[3]);
            r.y = interp_word(a00[kc].y, a01[kc].y, a10[kc].y, a11[kc].y, w[0], w[1], w[2], w[3]);
            r.z = interp_word(a00[kc].z, a01[kc].z, a10[kc].z, a11[kc].z, w[0], w[1], w[2], w[3]);
            r.w = interp_word(a00[kc].w, a01[kc].w, a10[kc].w, a11[kc].w, w[0], w[1], w[2], w[3]);
            if (kc == 0) b0 = __builtin_bit_cast(bf16x8, r);
            else         b1 = __builtin_bit_cast(bf16x8, r);
        }
    };
    int4 c00[2], c01[2], c10[2], c11[2];
    int4 n00[2], n01[2], n10[2], n11[2];
    floatx4 cw, nw;
#define STAGE_A(BUF, TAP) do {                                                 \
        const unsigned short* gs_ = Wkb2 + (TAP) * 8192 + wave * 2048 + lane * 8; \
        g2l16(gs_,         &BUF[wave * 2048]);                                 \
        g2l16(gs_ + 512,   &BUF[wave * 2048 + 512]);                           \
        g2l16(gs_ + 1024,  &BUF[wave * 2048 + 1024]);                          \
        g2l16(gs_ + 1536,  &BUF[wave * 2048 + 1536]);                          \
    } while (0)
#define BODY(TAP, RBUF, WBUF, LAST) do {                                       \
        asm volatile("s_waitcnt vmcnt(8)\n\ts_barrier" ::: "memory");          \
        if (!(LAST)) { STAGE_A(WBUF, (TAP) + 1); }                             \
        __builtin_amdgcn_sched_barrier(0);                                     \
        if (!(LAST)) stage((TAP) + 1, n00, n01, n10, n11, nw);                 \
        __builtin_amdgcn_sched_barrier(0);                                     \
        bf16x8 bf0, bf1;                                                       \
        makeB(c00, c01, c10, c11, cw, bf0, bf1);                               \
        _Pragma("unroll")                                                      \
        for (int mt = 0; mt < 8; mt++) {                                       \
            bf16x8 af = *(const bf16x8*)&RBUF[(mt * 2) * 512 + lane * 8];      \
            acc[mt] = __builtin_amdgcn_mfma_f32_16x16x32_bf16(af, bf0, acc[mt], 0, 0, 0); \
        }                                                                      \
        _Pragma("unroll")                                                      \
        for (int mt = 0; mt < 8; mt++) {                                       \
            bf16x8 af = *(const bf16x8*)&RBUF[(mt * 2 + 1) * 512 + lane * 8];  \
            acc[mt] = __builtin_amdgcn_mfma_f32_16x16x32_bf16(af, bf1, acc[mt], 0, 0, 0); \
        }                                                                      \
        if (!(LAST)) {                                                         \
            _Pragma("unroll")                                                  \
            for (int kc = 0; kc < 2; kc++) {                                   \
                c00[kc] = n00[kc]; c01[kc] = n01[kc];                          \
                c10[kc] = n10[kc]; c11[kc] = n11[kc];                          \
            }                                                                  \
            cw = nw;                                                           \
        }                                                                      \
    } while (0)
    __builtin_amdgcn_sched_barrier(0);
    STAGE_A(As0, 0);
    __builtin_amdgcn_sched_barrier(0);
    stage(0, c00, c01, c10, c11, cw);
#pragma unroll 1
    for (int t2 = 0; t2 < 4; t2++) {
        int tap = t2 * 2;
        BODY(tap,     As0, As1, false);
        BODY(tap + 1, As1, As0, false);
    }
    BODY(8, As0, As1, true);
#undef BODY
#undef STAGE_A
    float* outb = out + (size_t)b * 524288 + px;
#pragma unroll
    for (int mt = 0; mt < 8; mt++) {
        float4 bc = *(const float4*)(bias + mt * 16 + quad * 4);
        float bcv[4] = {bc.x, bc.y, bc.z, bc.w};
#pragma unroll
        for (int rg = 0; rg < 4; rg++) {
            int oc = mt * 16 + quad * 4 + rg;
            outb[oc * 4096] = acc[mt][rg] + bcv[rg];
        }
    }
}

extern "C" void kernel_launch(void* const* d_in, const int* in_sizes, int n_in,
                              void* d_out, int out_size, void* d_ws, size_t ws_size,
                              hipStream_t stream) {
    const float* x    = (const float*)d_in[0];
    const float* Woff = (const float*)d_in[1];
    const float* boff = (const float*)d_in[2];
    const float* Wk   = (const float*)d_in[3];
    const float* bk   = (const float*)d_in[4];
    float* out = (float*)d_out;

    char* ws = (char*)d_ws;
    unsigned short* xt    = (unsigned short*)ws;               // 8388608 B
    unsigned short* Wkb2  = (unsigned short*)(ws + 8388608);   // 147456 B
    unsigned short* Woffb = (unsigned short*)(ws + 8536064);   // 36864 B
    const size_t base = 8572928;                               // end of fixed region
    unsigned short* xo    = (unsigned short*)(ws + base);      // sampled B-matrix

    prep_all<<<1384, 256, 0, stream>>>(x, Wk, Woff, xt, Wkb2, Woffb);

    // pick largest image-chunk G whose xo fits the workspace
    const size_t per_img = (size_t)9 * 4096 * 64 * 2;          // 4,718,592 B
    int G = 0;
    for (int g = 16; g >= 1; g >>= 1)
        if (ws_size >= base + (size_t)g * per_img) { G = g; break; }

    if (G == 0) {
        fused_fallback<<<1024, 256, 0, stream>>>(xt, Wkb2, Woffb, boff, bk, out);
        return;
    }
    int chunkpx = G * 4096;
    for (int b0 = 0; b0 < 16; b0 += G) {
        sampler_kernel<<<G * 64, 256, 0, stream>>>(xt, Woffb, boff, xo, b0, chunkpx);
        gemm_kernel<<<G * 32, 256, 0, stream>>>(xo, Wkb2, bk, out, b0, chunkpx);
    }
}